// Round 3
// baseline (874.933 us; speedup 1.0000x reference)
//
#include <hip/hip_runtime.h>

// NodeMPNNLayer — persistent barrier-free bf16-MFMA edge kernel.
//   prep_weights: W1b/W2/W3 -> bf16 [n][swz(k)] in ws.
//   pq_kernel:    P' = x@W1[0:128]+b1, Q = x@W1[256:384]  (bf16).
//   edge_mfma:    250 persistent blocks x 20 tiles x 128 edges. All 3 weight
//                 mats resident in LDS (96 KB); 8 KB wave-private A buffer;
//                 NO per-tile barriers (waves own disjoint 32-row slices).
//                 P/Q gathers feed the MFMA C-operand; ea prefetched 1 tile
//                 ahead in regs; epilogue scatter-adds via global atomics.
//   node_fused:   dh=sums/max(cnt,1); LN; FF; LN (fp32, float4 LDS reads).

#define NE 640000
#define NN 10000
#define DD 128
#define HIDN 256
#define EPSF 1e-6f
#define TILES 20
#define EBLK 250   // EBLK*TILES*128 == NE

typedef __attribute__((ext_vector_type(8))) short short8;
typedef __attribute__((ext_vector_type(4))) float f32x4;

__device__ __forceinline__ unsigned short f2bf(float f) {
    union { float f; unsigned int u; } v; v.f = f;
    unsigned int r = v.u + 0x7FFFu + ((v.u >> 16) & 1u);
    return (unsigned short)(r >> 16);
}
__device__ __forceinline__ float bf2f(unsigned short h) {
    union { unsigned int u; float f; } v; v.u = ((unsigned int)h) << 16;
    return v.f;
}
__device__ __forceinline__ int swzcol(int row, int col) {
    return (((col >> 3) ^ (row & 7)) << 3) | (col & 7);
}
__device__ __forceinline__ const short8* frag(const unsigned short* buf,
                                              int row, int kc, int q) {
    int g = (kc * 4 + q) ^ (row & 7);
    return (const short8*)(buf + row * 128 + g * 8);
}

// ---------------------------------------------------------------------------
__global__ void prep_weights(const float* __restrict__ W1,
                             const float* __restrict__ W2,
                             const float* __restrict__ W3,
                             unsigned short* __restrict__ WT)
{
    int g = blockIdx.x * 256 + threadIdx.x;      // 3*16384 = 49152
    int layer = g >> 14, r = g & 16383;
    int n = r >> 7, k = r & 127;
    const float* W = (layer == 0) ? (W1 + 128 * DD) : (layer == 1 ? W2 : W3);
    WT[layer * 16384 + n * 128 + swzcol(n, k)] = f2bf(W[k * DD + n]);
}

// ---------------------------------------------------------------------------
// P' = x @ W1[0:128] + b1 ; Q = x @ W1[256:384]   (bf16 out). 16 nodes/block.
// ---------------------------------------------------------------------------
__global__ __launch_bounds__(256)
void pq_kernel(const float* __restrict__ x, const float* __restrict__ W1,
               const float* __restrict__ b1,
               unsigned short* __restrict__ Pb, unsigned short* __restrict__ Qb)
{
    __shared__ float sx[16][DD];
    const int t = threadIdx.x;
    const int nb = blockIdx.x * 16;

#pragma unroll
    for (int p = 0; p < 2; ++p) {
        int f = t + p * 256;                  // 512 float4 = 16 rows x 32
        int row = f >> 5, c4 = (f & 31) << 2;
        *(float4*)&sx[row][c4] = *(const float4*)(x + (long)(nb + row) * DD + c4);
    }
    __syncthreads();

    const int j  = t & 127;
    const int g8 = (t >> 7) << 3;             // node sub-group 0 or 8

    for (int pass = 0; pass < 2; ++pass) {
        const float* W = W1 + (pass ? 256 * DD : 0);
        float acc[8];
#pragma unroll
        for (int v = 0; v < 8; ++v) acc[v] = 0.f;
        for (int k4 = 0; k4 < DD; k4 += 4) {
            float w0 = W[(k4 + 0) * DD + j];
            float w1 = W[(k4 + 1) * DD + j];
            float w2 = W[(k4 + 2) * DD + j];
            float w3 = W[(k4 + 3) * DD + j];
#pragma unroll
            for (int v = 0; v < 8; ++v) {
                float4 hv = *(const float4*)&sx[g8 + v][k4];
                acc[v] = fmaf(hv.x, w0, acc[v]);
                acc[v] = fmaf(hv.y, w1, acc[v]);
                acc[v] = fmaf(hv.z, w2, acc[v]);
                acc[v] = fmaf(hv.w, w3, acc[v]);
            }
        }
        unsigned short* Out = pass ? Qb : Pb;
        float bb = pass ? 0.f : b1[j];
#pragma unroll
        for (int v = 0; v < 8; ++v)
            Out[(long)(nb + g8 + v) * DD + j] = f2bf(acc[v] + bb);
    }
}

// ---------------------------------------------------------------------------
// Persistent edge kernel. Wave w owns rows [32w,32w+32) of every tile.
// ---------------------------------------------------------------------------
__global__ __launch_bounds__(256, 1)
void edge_mfma(const float* __restrict__ ea, const int* __restrict__ ei,
               const unsigned short* __restrict__ WT,
               const unsigned short* __restrict__ Pb,
               const unsigned short* __restrict__ Qb,
               const float* __restrict__ b2, const float* __restrict__ b3,
               float* __restrict__ sums, float* __restrict__ cnt)
{
    __shared__ unsigned short sW[3 * 128 * 128];   // 96 KB, resident all tiles
    __shared__ unsigned short sA[4][32 * 128];     // 32 KB, wave-private

    const int t = threadIdx.x;
    const int wave = t >> 6, lane = t & 63;
    const int ln = lane & 15, q = lane >> 4;
    const int r0g = wave * 32;
    unsigned short* myA = sA[wave];

    {   // one-time W load — the ONLY barrier in the kernel
        const uint4* s = (const uint4*)WT;
        uint4* d = (uint4*)sW;
#pragma unroll
        for (int p = 0; p < 24; ++p) d[t + p * 256] = s[t + p * 256];
    }
    __syncthreads();

    int rowoff[8];
#pragma unroll
    for (int r = 0; r < 8; ++r) rowoff[r] = (r >> 2) * 16 + q * 4 + (r & 3);

    float bv2[8], bv3[8];
#pragma unroll
    for (int ct = 0; ct < 8; ++ct) { bv2[ct] = b2[ct * 16 + ln]; bv3[ct] = b3[ct * 16 + ln]; }

    const long tb0 = (long)blockIdx.x * TILES * 128;

    // ---- prefetch tile 0 ----
    float4 Aq[16];
    int dstR[8], srcR[8];
#pragma unroll
    for (int jj = 0; jj < 16; ++jj) {
        int f = lane + jj * 64;
        int srow = f >> 5, c4 = (f & 31) << 2;
        Aq[jj] = *(const float4*)(ea + (tb0 + r0g + srow) * DD + c4);
    }
#pragma unroll
    for (int r = 0; r < 8; ++r) {
        dstR[r] = ei[(long)NE + tb0 + r0g + rowoff[r]];
        srcR[r] = ei[tb0 + r0g + rowoff[r]];
    }

    for (int it = 0; it < TILES; ++it) {
        const long nb_ = tb0 + (long)((it + 1 < TILES) ? it + 1 : it) * 128;

        // ---- P/Q gathers for current tile (feed MFMA C-init) ----
        unsigned short pU[64], qU[64];
#pragma unroll
        for (int r = 0; r < 8; ++r) {
            long dof = (long)dstR[r] * DD, sof = (long)srcR[r] * DD;
#pragma unroll
            for (int ct = 0; ct < 8; ++ct) {
                pU[r * 8 + ct] = Pb[dof + ct * 16 + ln];
                qU[r * 8 + ct] = Qb[sof + ct * 16 + ln];
            }
        }

        // ---- stage current A tile (regs -> bf16 swizzled LDS, wave-private) ----
#pragma unroll
        for (int jj = 0; jj < 16; ++jj) {
            int f = lane + jj * 64;
            int srow = f >> 5, c4 = (f & 31) << 2;
            float4 v = Aq[jj];
            uint2 pk;
            pk.x = (unsigned)f2bf(v.x) | ((unsigned)f2bf(v.y) << 16);
            pk.y = (unsigned)f2bf(v.z) | ((unsigned)f2bf(v.w) << 16);
            *(uint2*)(myA + srow * 128 + swzcol(srow, c4)) = pk;
        }
        __builtin_amdgcn_wave_barrier();

        // ---- C-init: acc = P'[dst] + Q[src] (bias b1 folded into P') ----
        f32x4 acc[2][8];
#pragma unroll
        for (int rt = 0; rt < 2; ++rt)
#pragma unroll
            for (int ct = 0; ct < 8; ++ct)
#pragma unroll
                for (int rg = 0; rg < 4; ++rg)
                    acc[rt][ct][rg] = bf2f(pU[(rt * 4 + rg) * 8 + ct]) +
                                      bf2f(qU[(rt * 4 + rg) * 8 + ct]);

        // ---- prefetch next tile (consumed next iteration) ----
#pragma unroll
        for (int jj = 0; jj < 16; ++jj) {
            int f = lane + jj * 64;
            int srow = f >> 5, c4 = (f & 31) << 2;
            Aq[jj] = *(const float4*)(ea + (nb_ + r0g + srow) * DD + c4);
        }
        int ndst[8], nsrc[8];
#pragma unroll
        for (int r = 0; r < 8; ++r) {
            ndst[r] = ei[(long)NE + nb_ + r0g + rowoff[r]];
            nsrc[r] = ei[nb_ + r0g + rowoff[r]];
        }

        // ---- layer 1: acc += bf16(ea) @ W1b^T ----
#pragma unroll
        for (int kc = 0; kc < 4; ++kc) {
            short8 a0 = *frag(myA, ln, kc, q);
            short8 a1 = *frag(myA, 16 + ln, kc, q);
#pragma unroll
            for (int ct = 0; ct < 8; ++ct) {
                short8 b = *frag(sW, ct * 16 + ln, kc, q);
                acc[0][ct] = __builtin_amdgcn_mfma_f32_16x16x32_bf16(a0, b, acc[0][ct], 0, 0, 0);
                acc[1][ct] = __builtin_amdgcn_mfma_f32_16x16x32_bf16(a1, b, acc[1][ct], 0, 0, 0);
            }
        }
        __builtin_amdgcn_wave_barrier();
        // epi1: relu -> myA (in-place, wave-private)
#pragma unroll
        for (int rt = 0; rt < 2; ++rt)
#pragma unroll
            for (int rg = 0; rg < 4; ++rg) {
                int row = rt * 16 + q * 4 + rg;
#pragma unroll
                for (int ct = 0; ct < 8; ++ct) {
                    int col = ct * 16 + ln;
                    myA[row * 128 + swzcol(row, col)] =
                        f2bf(fmaxf(acc[rt][ct][rg], 0.f));
                }
            }
        __builtin_amdgcn_wave_barrier();

        // ---- layer 2 ----
#pragma unroll
        for (int rt = 0; rt < 2; ++rt)
#pragma unroll
            for (int ct = 0; ct < 8; ++ct) acc[rt][ct] = (f32x4)(0.f);
#pragma unroll
        for (int kc = 0; kc < 4; ++kc) {
            short8 a0 = *frag(myA, ln, kc, q);
            short8 a1 = *frag(myA, 16 + ln, kc, q);
#pragma unroll
            for (int ct = 0; ct < 8; ++ct) {
                short8 b = *frag(sW + 16384, ct * 16 + ln, kc, q);
                acc[0][ct] = __builtin_amdgcn_mfma_f32_16x16x32_bf16(a0, b, acc[0][ct], 0, 0, 0);
                acc[1][ct] = __builtin_amdgcn_mfma_f32_16x16x32_bf16(a1, b, acc[1][ct], 0, 0, 0);
            }
        }
        __builtin_amdgcn_wave_barrier();
        // epi2: relu(acc + b2) -> myA
#pragma unroll
        for (int rt = 0; rt < 2; ++rt)
#pragma unroll
            for (int rg = 0; rg < 4; ++rg) {
                int row = rt * 16 + q * 4 + rg;
#pragma unroll
                for (int ct = 0; ct < 8; ++ct) {
                    int col = ct * 16 + ln;
                    myA[row * 128 + swzcol(row, col)] =
                        f2bf(fmaxf(acc[rt][ct][rg] + bv2[ct], 0.f));
                }
            }
        __builtin_amdgcn_wave_barrier();

        // ---- layer 3 ----
#pragma unroll
        for (int rt = 0; rt < 2; ++rt)
#pragma unroll
            for (int ct = 0; ct < 8; ++ct) acc[rt][ct] = (f32x4)(0.f);
#pragma unroll
        for (int kc = 0; kc < 4; ++kc) {
            short8 a0 = *frag(myA, ln, kc, q);
            short8 a1 = *frag(myA, 16 + ln, kc, q);
#pragma unroll
            for (int ct = 0; ct < 8; ++ct) {
                short8 b = *frag(sW + 2 * 16384, ct * 16 + ln, kc, q);
                acc[0][ct] = __builtin_amdgcn_mfma_f32_16x16x32_bf16(a0, b, acc[0][ct], 0, 0, 0);
                acc[1][ct] = __builtin_amdgcn_mfma_f32_16x16x32_bf16(a1, b, acc[1][ct], 0, 0, 0);
            }
        }
        // epi3: scatter-add (acc + b3)
#pragma unroll
        for (int rt = 0; rt < 2; ++rt)
#pragma unroll
            for (int rg = 0; rg < 4; ++rg) {
                long dof = (long)dstR[rt * 4 + rg] * DD;
#pragma unroll
                for (int ct = 0; ct < 8; ++ct)
                    atomicAdd(sums + dof + ct * 16 + ln,
                              acc[rt][ct][rg] + bv3[ct]);
            }
        if (ln == 0) {
#pragma unroll
            for (int r = 0; r < 8; ++r) atomicAdd(cnt + dstR[r], 1.0f);
        }
#pragma unroll
        for (int r = 0; r < 8; ++r) { dstR[r] = ndst[r]; srcR[r] = nsrc[r]; }
    }
}

// ---------------------------------------------------------------------------
// Node stage: dh + LN1 + FF + LN2, fp32, 8 nodes/block, float4 LDS reads.
// ---------------------------------------------------------------------------
__global__ __launch_bounds__(256)
void node_fused(const float* __restrict__ x,
                const float* __restrict__ sums, const float* __restrict__ cnt,
                const float* __restrict__ F1, const float* __restrict__ bf1,
                const float* __restrict__ F2, const float* __restrict__ bf2,
                const float* __restrict__ g0, const float* __restrict__ be0,
                const float* __restrict__ g1, const float* __restrict__ be1,
                float* __restrict__ out)
{
    constexpr int NPB = 8;
    __shared__ float sh[NPB][DD];
    __shared__ float shid[NPB][HIDN];
    __shared__ float sz[NPB][DD];

    const int t = threadIdx.x;
    const int wave = t >> 6, lane = t & 63;
    const int half = lane >> 5, l2 = lane & 31;
    const int nl = wave * 2 + half;
    const int node = blockIdx.x * NPB + nl;
    const long base = (long)node * DD;

    float inv = 1.0f / fmaxf(cnt[node], 1.0f);
    float y[4], s = 0.f, ss = 0.f;
#pragma unroll
    for (int e = 0; e < 4; ++e) {
        int c = l2 + 32 * e;
        y[e] = x[base + c] + sums[base + c] * inv;
        s += y[e]; ss += y[e] * y[e];
    }
#pragma unroll
    for (int off = 16; off > 0; off >>= 1) {
        s += __shfl_down(s, off, 32); ss += __shfl_down(ss, off, 32);
    }
    s = __shfl(s, 0, 32); ss = __shfl(ss, 0, 32);
    float mean = s * (1.0f / DD);
    float var  = ss * (1.0f / DD) - mean * mean;
    float rstd = rsqrtf(var + EPSF);
#pragma unroll
    for (int e = 0; e < 4; ++e) {
        int c = l2 + 32 * e;
        sh[nl][c] = (y[e] - mean) * rstd * g0[c] + be0[c];
    }
    __syncthreads();

    float hacc[NPB];
    float bb = bf1[t];
#pragma unroll
    for (int v = 0; v < NPB; ++v) hacc[v] = bb;
    for (int k4 = 0; k4 < DD; k4 += 4) {
        float w0 = F1[(long)(k4 + 0) * HIDN + t];
        float w1 = F1[(long)(k4 + 1) * HIDN + t];
        float w2 = F1[(long)(k4 + 2) * HIDN + t];
        float w3 = F1[(long)(k4 + 3) * HIDN + t];
#pragma unroll
        for (int v = 0; v < NPB; ++v) {
            float4 hv = *(const float4*)&sh[v][k4];
            hacc[v] = fmaf(hv.x, w0, hacc[v]);
            hacc[v] = fmaf(hv.y, w1, hacc[v]);
            hacc[v] = fmaf(hv.z, w2, hacc[v]);
            hacc[v] = fmaf(hv.w, w3, hacc[v]);
        }
    }
#pragma unroll
    for (int v = 0; v < NPB; ++v) shid[v][t] = fmaxf(hacc[v], 0.f);
    __syncthreads();

    const int col = t & (DD - 1);
    const int grp = (t >> 7) * 4;
    float o[4];
#pragma unroll
    for (int v = 0; v < 4; ++v) o[v] = bf2[col];
    for (int k4 = 0; k4 < HIDN; k4 += 4) {
        float w0 = F2[(long)(k4 + 0) * DD + col];
        float w1 = F2[(long)(k4 + 1) * DD + col];
        float w2 = F2[(long)(k4 + 2) * DD + col];
        float w3 = F2[(long)(k4 + 3) * DD + col];
#pragma unroll
        for (int v = 0; v < 4; ++v) {
            float4 hv = *(const float4*)&shid[grp + v][k4];
            o[v] = fmaf(hv.x, w0, o[v]);
            o[v] = fmaf(hv.y, w1, o[v]);
            o[v] = fmaf(hv.z, w2, o[v]);
            o[v] = fmaf(hv.w, w3, o[v]);
        }
    }
#pragma unroll
    for (int v = 0; v < 4; ++v) sz[grp + v][col] = sh[grp + v][col] + o[v];
    __syncthreads();

    float z[4]; s = 0.f; ss = 0.f;
#pragma unroll
    for (int e = 0; e < 4; ++e) {
        int c = l2 + 32 * e;
        z[e] = sz[nl][c]; s += z[e]; ss += z[e] * z[e];
    }
#pragma unroll
    for (int off = 16; off > 0; off >>= 1) {
        s += __shfl_down(s, off, 32); ss += __shfl_down(ss, off, 32);
    }
    s = __shfl(s, 0, 32); ss = __shfl(ss, 0, 32);
    mean = s * (1.0f / DD);
    var  = ss * (1.0f / DD) - mean * mean;
    rstd = rsqrtf(var + EPSF);
#pragma unroll
    for (int e = 0; e < 4; ++e) {
        int c = l2 + 32 * e;
        out[base + c] = (z[e] - mean) * rstd * g1[c] + be1[c];
    }
}

extern "C" void kernel_launch(void* const* d_in, const int* in_sizes, int n_in,
                              void* d_out, int out_size, void* d_ws, size_t ws_size,
                              hipStream_t stream)
{
    const float* x   = (const float*)d_in[0];
    const int*   ei  = (const int*)  d_in[1];
    const float* ea  = (const float*)d_in[2];
    const float* W1  = (const float*)d_in[3];
    const float* b1  = (const float*)d_in[4];
    const float* W2  = (const float*)d_in[5];
    const float* b2  = (const float*)d_in[6];
    const float* W3  = (const float*)d_in[7];
    const float* b3  = (const float*)d_in[8];
    const float* F1  = (const float*)d_in[9];
    const float* bf1 = (const float*)d_in[10];
    const float* F2  = (const float*)d_in[11];
    const float* bf2 = (const float*)d_in[12];
    const float* g0  = (const float*)d_in[13];
    const float* be0 = (const float*)d_in[14];
    const float* g1  = (const float*)d_in[15];
    const float* be1 = (const float*)d_in[16];
    float* out = (float*)d_out;

    char* ws = (char*)d_ws;
    float*          sums = (float*)(ws);                       // 5,120,000 B
    float*          cnt  = (float*)(ws + 5120000);             //    40,000 B
    unsigned short* WT   = (unsigned short*)(ws + 5160192);    //    98,304 B
    unsigned short* Pb   = (unsigned short*)(ws + 5258752);    // 2,560,000 B
    unsigned short* Qb   = (unsigned short*)(ws + 7818752);    // 2,560,000 B

    hipMemsetAsync(ws, 0, 5160000, stream);                    // sums + cnt
    prep_weights<<<192, 256, 0, stream>>>(W1, W2, W3, WT);
    pq_kernel<<<NN / 16, 256, 0, stream>>>(x, W1, b1, Pb, Qb);
    edge_mfma<<<EBLK, 256, 0, stream>>>(ea, ei, WT, Pb, Qb, b2, b3, sums, cnt);
    node_fused<<<NN / 8, 256, 0, stream>>>(x, sums, cnt, F1, bf1, F2, bf2,
                                           g0, be0, g1, be1, out);
}

// Round 4
// 807.851 us; speedup vs baseline: 1.0830x; 1.0830x over previous
//
#include <hip/hip_runtime.h>

// NodeMPNNLayer — R4: 8-wave barrier-free MFMA edge kernel, vectorized P/Q.
//   prep_pq:   blocks [0,192): W1b/W2/W3 -> bf16 [n][swz(k)] (WT).
//              blocks [192,817): P'=x@W1[0:128]+b1, Q=x@W1[256:384], stored
//              C-fragment-permuted: Pp[node*128 + (j&15)*8 + (j>>4)].
//   edge_mfma: 250 blocks x 512 thr x 10 tiles x 256 edges. W resident in
//              96 KB LDS; 8 KB/wave act buffer (160 KB total, 1 blk/CU,
//              8 waves/CU). Layer-1 A-frags direct from global (fp32->bf16
//              in regs). P/Q C-init via one uint4 gather per row. Only one
//              __syncthreads (after W load).
//   node_fused: dh=sums/max(cnt,1); LN; FF; LN (fp32).

#define NE 640000
#define NN 10000
#define DD 128
#define HIDN 256
#define EPSF 1e-6f
#define TILES4 10
#define EBLK4 250   // 250 * 10 * 256 == NE

typedef __attribute__((ext_vector_type(8))) short short8;
typedef __attribute__((ext_vector_type(4))) float f32x4;

__device__ __forceinline__ unsigned short f2bf(float f) {
    union { float f; unsigned int u; } v; v.f = f;
    unsigned int r = v.u + 0x7FFFu + ((v.u >> 16) & 1u);
    return (unsigned short)(r >> 16);
}
__device__ __forceinline__ float bf2f(unsigned short h) {
    union { unsigned int u; float f; } v; v.u = ((unsigned int)h) << 16;
    return v.f;
}
__device__ __forceinline__ int swzcol(int row, int col) {
    return (((col >> 3) ^ (row & 7)) << 3) | (col & 7);
}
__device__ __forceinline__ const short8* frag(const unsigned short* buf,
                                              int row, int kc, int q) {
    int g = (kc * 4 + q) ^ (row & 7);
    return (const short8*)(buf + row * 128 + g * 8);
}

// ---------------------------------------------------------------------------
// prep (192 blocks) + pq (625 blocks) fused into one dispatch.
// ---------------------------------------------------------------------------
__global__ __launch_bounds__(256)
void prep_pq(const float* __restrict__ W1, const float* __restrict__ W2,
             const float* __restrict__ W3, const float* __restrict__ b1,
             const float* __restrict__ x,
             unsigned short* __restrict__ WT,
             unsigned short* __restrict__ Pp, unsigned short* __restrict__ Qp)
{
    const int t = threadIdx.x;
    if (blockIdx.x < 192) {
        int g = blockIdx.x * 256 + t;            // 3*16384 = 49152
        int layer = g >> 14, r = g & 16383;
        int n = r >> 7, k = r & 127;
        const float* W = (layer == 0) ? (W1 + 128 * DD) : (layer == 1 ? W2 : W3);
        WT[layer * 16384 + n * 128 + swzcol(n, k)] = f2bf(W[k * DD + n]);
        return;
    }
    __shared__ float sx[16][DD];
    const int nb = (blockIdx.x - 192) * 16;

#pragma unroll
    for (int p = 0; p < 2; ++p) {
        int f = t + p * 256;                     // 512 float4 = 16 rows x 32
        int row = f >> 5, c4 = (f & 31) << 2;
        *(float4*)&sx[row][c4] = *(const float4*)(x + (long)(nb + row) * DD + c4);
    }
    __syncthreads();

    const int j  = t & 127;
    const int g8 = (t >> 7) << 3;
    const int pj = ((j & 15) << 3) + (j >> 4);   // permuted in-row position

    for (int pass = 0; pass < 2; ++pass) {
        const float* W = W1 + (pass ? 256 * DD : 0);
        float acc[8];
#pragma unroll
        for (int v = 0; v < 8; ++v) acc[v] = 0.f;
        for (int k4 = 0; k4 < DD; k4 += 4) {
            float w0 = W[(k4 + 0) * DD + j];
            float w1 = W[(k4 + 1) * DD + j];
            float w2 = W[(k4 + 2) * DD + j];
            float w3 = W[(k4 + 3) * DD + j];
#pragma unroll
            for (int v = 0; v < 8; ++v) {
                float4 hv = *(const float4*)&sx[g8 + v][k4];
                acc[v] = fmaf(hv.x, w0, acc[v]);
                acc[v] = fmaf(hv.y, w1, acc[v]);
                acc[v] = fmaf(hv.z, w2, acc[v]);
                acc[v] = fmaf(hv.w, w3, acc[v]);
            }
        }
        unsigned short* Out = pass ? Qp : Pp;
        float bb = pass ? 0.f : b1[j];
#pragma unroll
        for (int v = 0; v < 8; ++v)
            Out[(long)(nb + g8 + v) * 128 + pj] = f2bf(acc[v] + bb);
    }
}

// ---------------------------------------------------------------------------
// Edge kernel: 512 threads (8 waves), wave w owns rows [32w,32w+32) of each
// 256-edge tile. 160 KB LDS. Barrier-free after W load.
// ---------------------------------------------------------------------------
__global__ __launch_bounds__(512, 2)
void edge_mfma(const float* __restrict__ ea, const int* __restrict__ ei,
               const unsigned short* __restrict__ WT,
               const unsigned short* __restrict__ Pp,
               const unsigned short* __restrict__ Qp,
               const float* __restrict__ b2, const float* __restrict__ b3,
               float* __restrict__ sums, float* __restrict__ cnt)
{
    __shared__ unsigned short sW[3 * 16384];     // 96 KB: W1b, W2, W3
    __shared__ unsigned short sAct[8 * 4096];    // 64 KB: 8 KB per wave

    const int t = threadIdx.x;
    const int wave = t >> 6, lane = t & 63;
    const int ln = lane & 15, q = lane >> 4;
    unsigned short* myA = sAct + wave * 4096;

    {   // one-time W load — the ONLY __syncthreads
        const uint4* s = (const uint4*)WT;
        uint4* d = (uint4*)sW;
#pragma unroll
        for (int p = 0; p < 12; ++p) d[t + p * 512] = s[t + p * 512];
    }
    __syncthreads();

    float bv2[8], bv3[8];
#pragma unroll
    for (int ct = 0; ct < 8; ++ct) {
        bv2[ct] = b2[ct * 16 + ln];
        bv3[ct] = b3[ct * 16 + ln];
    }

    const long blkbase = (long)blockIdx.x * (TILES4 * 256);

    // ---- prefetch tile 0: A rows + indices ----
    float4 Aq[16];
    int dstR[8], srcR[8];
    {
        long tb = blkbase;
#pragma unroll
        for (int rt = 0; rt < 2; ++rt)
#pragma unroll
            for (int kc = 0; kc < 4; ++kc) {
                long row = tb + wave * 32 + rt * 16 + ln;
                const float* p = ea + row * DD + kc * 32 + q * 8;
                Aq[rt * 8 + kc * 2 + 0] = *(const float4*)(p);
                Aq[rt * 8 + kc * 2 + 1] = *(const float4*)(p + 4);
            }
#pragma unroll
        for (int r = 0; r < 8; ++r) {
            long row = tb + wave * 32 + (r >> 2) * 16 + q * 4 + (r & 3);
            dstR[r] = ei[(long)NE + row];
            srcR[r] = ei[row];
        }
    }

    for (int it = 0; it < TILES4; ++it) {
        // ---- convert current A to bf16 fragments ----
        short8 af[2][4];
#pragma unroll
        for (int rt = 0; rt < 2; ++rt)
#pragma unroll
            for (int kc = 0; kc < 4; ++kc) {
                const float* f0 = (const float*)&Aq[rt * 8 + kc * 2];
                short8 v;
#pragma unroll
                for (int jj = 0; jj < 8; ++jj) v[jj] = (short)f2bf(f0[jj]);
                af[rt][kc] = v;
            }

        // ---- C-init: acc = P'[dst] + Q[src] (one uint4 gather per row) ----
        f32x4 acc[2][8];
#pragma unroll
        for (int r = 0; r < 8; ++r) {
            uint4 pv = *(const uint4*)(Pp + (long)dstR[r] * 128 + ln * 8);
            uint4 qv = *(const uint4*)(Qp + (long)srcR[r] * 128 + ln * 8);
            const unsigned short* pe = (const unsigned short*)&pv;
            const unsigned short* qe = (const unsigned short*)&qv;
#pragma unroll
            for (int ct = 0; ct < 8; ++ct)
                acc[r >> 2][ct][r & 3] = bf2f(pe[ct]) + bf2f(qe[ct]);
        }

        // ---- prefetch next tile ----
        long nb_ = blkbase + (long)((it + 1 < TILES4) ? it + 1 : it) * 256;
        int ndst[8], nsrc[8];
#pragma unroll
        for (int rt = 0; rt < 2; ++rt)
#pragma unroll
            for (int kc = 0; kc < 4; ++kc) {
                long row = nb_ + wave * 32 + rt * 16 + ln;
                const float* p = ea + row * DD + kc * 32 + q * 8;
                Aq[rt * 8 + kc * 2 + 0] = *(const float4*)(p);
                Aq[rt * 8 + kc * 2 + 1] = *(const float4*)(p + 4);
            }
#pragma unroll
        for (int r = 0; r < 8; ++r) {
            long row = nb_ + wave * 32 + (r >> 2) * 16 + q * 4 + (r & 3);
            ndst[r] = ei[(long)NE + row];
            nsrc[r] = ei[row];
        }

        // ---- layer 1: acc += bf16(ea) @ W1b^T (A from regs, B from LDS) ----
#pragma unroll
        for (int kc = 0; kc < 4; ++kc)
#pragma unroll
            for (int ct = 0; ct < 8; ++ct) {
                short8 b = *frag(sW, ct * 16 + ln, kc, q);
                acc[0][ct] = __builtin_amdgcn_mfma_f32_16x16x32_bf16(af[0][kc], b, acc[0][ct], 0, 0, 0);
                acc[1][ct] = __builtin_amdgcn_mfma_f32_16x16x32_bf16(af[1][kc], b, acc[1][ct], 0, 0, 0);
            }
        // epi1: relu -> act (wave-private)
#pragma unroll
        for (int rt = 0; rt < 2; ++rt)
#pragma unroll
            for (int rg = 0; rg < 4; ++rg) {
                int row = rt * 16 + q * 4 + rg;
#pragma unroll
                for (int ct = 0; ct < 8; ++ct) {
                    int col = ct * 16 + ln;
                    myA[row * 128 + swzcol(row, col)] =
                        f2bf(fmaxf(acc[rt][ct][rg], 0.f));
                }
            }
        __builtin_amdgcn_wave_barrier();

        // ---- layer 2 ----
#pragma unroll
        for (int rt = 0; rt < 2; ++rt)
#pragma unroll
            for (int ct = 0; ct < 8; ++ct) acc[rt][ct] = (f32x4)(0.f);
#pragma unroll
        for (int kc = 0; kc < 4; ++kc) {
            short8 a0 = *frag(myA, ln, kc, q);
            short8 a1 = *frag(myA, 16 + ln, kc, q);
#pragma unroll
            for (int ct = 0; ct < 8; ++ct) {
                short8 b = *frag(sW + 16384, ct * 16 + ln, kc, q);
                acc[0][ct] = __builtin_amdgcn_mfma_f32_16x16x32_bf16(a0, b, acc[0][ct], 0, 0, 0);
                acc[1][ct] = __builtin_amdgcn_mfma_f32_16x16x32_bf16(a1, b, acc[1][ct], 0, 0, 0);
            }
        }
        __builtin_amdgcn_wave_barrier();
        // epi2: relu(acc + b2) -> act
#pragma unroll
        for (int rt = 0; rt < 2; ++rt)
#pragma unroll
            for (int rg = 0; rg < 4; ++rg) {
                int row = rt * 16 + q * 4 + rg;
#pragma unroll
                for (int ct = 0; ct < 8; ++ct) {
                    int col = ct * 16 + ln;
                    myA[row * 128 + swzcol(row, col)] =
                        f2bf(fmaxf(acc[rt][ct][rg] + bv2[ct], 0.f));
                }
            }
        __builtin_amdgcn_wave_barrier();

        // ---- layer 3 ----
#pragma unroll
        for (int rt = 0; rt < 2; ++rt)
#pragma unroll
            for (int ct = 0; ct < 8; ++ct) acc[rt][ct] = (f32x4)(0.f);
#pragma unroll
        for (int kc = 0; kc < 4; ++kc) {
            short8 a0 = *frag(myA, ln, kc, q);
            short8 a1 = *frag(myA, 16 + ln, kc, q);
#pragma unroll
            for (int ct = 0; ct < 8; ++ct) {
                short8 b = *frag(sW + 32768, ct * 16 + ln, kc, q);
                acc[0][ct] = __builtin_amdgcn_mfma_f32_16x16x32_bf16(a0, b, acc[0][ct], 0, 0, 0);
                acc[1][ct] = __builtin_amdgcn_mfma_f32_16x16x32_bf16(a1, b, acc[1][ct], 0, 0, 0);
            }
        }
        // epi3: scatter-add (acc + b3); per-row count
#pragma unroll
        for (int rt = 0; rt < 2; ++rt)
#pragma unroll
            for (int rg = 0; rg < 4; ++rg) {
                long dof = (long)dstR[rt * 4 + rg] * DD;
#pragma unroll
                for (int ct = 0; ct < 8; ++ct)
                    atomicAdd(sums + dof + ct * 16 + ln,
                              acc[rt][ct][rg] + bv3[ct]);
            }
        if (ln == 0) {
#pragma unroll
            for (int r = 0; r < 8; ++r) atomicAdd(cnt + dstR[r], 1.0f);
        }
#pragma unroll
        for (int r = 0; r < 8; ++r) { dstR[r] = ndst[r]; srcR[r] = nsrc[r]; }
    }
}

// ---------------------------------------------------------------------------
// Node stage: dh + LN1 + FF + LN2, fp32, 8 nodes/block.
// ---------------------------------------------------------------------------
__global__ __launch_bounds__(256)
void node_fused(const float* __restrict__ x,
                const float* __restrict__ sums, const float* __restrict__ cnt,
                const float* __restrict__ F1, const float* __restrict__ bf1,
                const float* __restrict__ F2, const float* __restrict__ bf2,
                const float* __restrict__ g0, const float* __restrict__ be0,
                const float* __restrict__ g1, const float* __restrict__ be1,
                float* __restrict__ out)
{
    constexpr int NPB = 8;
    __shared__ float sh[NPB][DD];
    __shared__ float shid[NPB][HIDN];
    __shared__ float sz[NPB][DD];

    const int t = threadIdx.x;
    const int wave = t >> 6, lane = t & 63;
    const int half = lane >> 5, l2 = lane & 31;
    const int nl = wave * 2 + half;
    const int node = blockIdx.x * NPB + nl;
    const long base = (long)node * DD;

    float inv = 1.0f / fmaxf(cnt[node], 1.0f);
    float y[4], s = 0.f, ss = 0.f;
#pragma unroll
    for (int e = 0; e < 4; ++e) {
        int c = l2 + 32 * e;
        y[e] = x[base + c] + sums[base + c] * inv;
        s += y[e]; ss += y[e] * y[e];
    }
#pragma unroll
    for (int off = 16; off > 0; off >>= 1) {
        s += __shfl_down(s, off, 32); ss += __shfl_down(ss, off, 32);
    }
    s = __shfl(s, 0, 32); ss = __shfl(ss, 0, 32);
    float mean = s * (1.0f / DD);
    float var  = ss * (1.0f / DD) - mean * mean;
    float rstd = rsqrtf(var + EPSF);
#pragma unroll
    for (int e = 0; e < 4; ++e) {
        int c = l2 + 32 * e;
        sh[nl][c] = (y[e] - mean) * rstd * g0[c] + be0[c];
    }
    __syncthreads();

    float hacc[NPB];
    float bb = bf1[t];
#pragma unroll
    for (int v = 0; v < NPB; ++v) hacc[v] = bb;
    for (int k4 = 0; k4 < DD; k4 += 4) {
        float w0 = F1[(long)(k4 + 0) * HIDN + t];
        float w1 = F1[(long)(k4 + 1) * HIDN + t];
        float w2 = F1[(long)(k4 + 2) * HIDN + t];
        float w3 = F1[(long)(k4 + 3) * HIDN + t];
#pragma unroll
        for (int v = 0; v < NPB; ++v) {
            float4 hv = *(const float4*)&sh[v][k4];
            hacc[v] = fmaf(hv.x, w0, hacc[v]);
            hacc[v] = fmaf(hv.y, w1, hacc[v]);
            hacc[v] = fmaf(hv.z, w2, hacc[v]);
            hacc[v] = fmaf(hv.w, w3, hacc[v]);
        }
    }
#pragma unroll
    for (int v = 0; v < NPB; ++v) shid[v][t] = fmaxf(hacc[v], 0.f);
    __syncthreads();

    const int col = t & (DD - 1);
    const int grp = (t >> 7) * 4;
    float o[4];
#pragma unroll
    for (int v = 0; v < 4; ++v) o[v] = bf2[col];
    for (int k4 = 0; k4 < HIDN; k4 += 4) {
        float w0 = F2[(long)(k4 + 0) * DD + col];
        float w1 = F2[(long)(k4 + 1) * DD + col];
        float w2 = F2[(long)(k4 + 2) * DD + col];
        float w3 = F2[(long)(k4 + 3) * DD + col];
#pragma unroll
        for (int v = 0; v < 4; ++v) {
            float4 hv = *(const float4*)&shid[grp + v][k4];
            o[v] = fmaf(hv.x, w0, o[v]);
            o[v] = fmaf(hv.y, w1, o[v]);
            o[v] = fmaf(hv.z, w2, o[v]);
            o[v] = fmaf(hv.w, w3, o[v]);
        }
    }
#pragma unroll
    for (int v = 0; v < 4; ++v) sz[grp + v][col] = sh[grp + v][col] + o[v];
    __syncthreads();

    float z[4]; s = 0.f; ss = 0.f;
#pragma unroll
    for (int e = 0; e < 4; ++e) {
        int c = l2 + 32 * e;
        z[e] = sz[nl][c]; s += z[e]; ss += z[e] * z[e];
    }
#pragma unroll
    for (int off = 16; off > 0; off >>= 1) {
        s += __shfl_down(s, off, 32); ss += __shfl_down(ss, off, 32);
    }
    s = __shfl(s, 0, 32); ss = __shfl(ss, 0, 32);
    mean = s * (1.0f / DD);
    var  = ss * (1.0f / DD) - mean * mean;
    rstd = rsqrtf(var + EPSF);
#pragma unroll
    for (int e = 0; e < 4; ++e) {
        int c = l2 + 32 * e;
        out[base + c] = (z[e] - mean) * rstd * g1[c] + be1[c];
    }
}

extern "C" void kernel_launch(void* const* d_in, const int* in_sizes, int n_in,
                              void* d_out, int out_size, void* d_ws, size_t ws_size,
                              hipStream_t stream)
{
    const float* x   = (const float*)d_in[0];
    const int*   ei  = (const int*)  d_in[1];
    const float* ea  = (const float*)d_in[2];
    const float* W1  = (const float*)d_in[3];
    const float* b1  = (const float*)d_in[4];
    const float* W2  = (const float*)d_in[5];
    const float* b2  = (const float*)d_in[6];
    const float* W3  = (const float*)d_in[7];
    const float* b3  = (const float*)d_in[8];
    const float* F1  = (const float*)d_in[9];
    const float* bf1 = (const float*)d_in[10];
    const float* F2  = (const float*)d_in[11];
    const float* bf2 = (const float*)d_in[12];
    const float* g0  = (const float*)d_in[13];
    const float* be0 = (const float*)d_in[14];
    const float* g1  = (const float*)d_in[15];
    const float* be1 = (const float*)d_in[16];
    float* out = (float*)d_out;

    char* ws = (char*)d_ws;
    float*          sums = (float*)(ws);                       // 5,120,000 B
    float*          cnt  = (float*)(ws + 5120000);             //    40,000 B
    unsigned short* WT   = (unsigned short*)(ws + 5160192);    //    98,304 B
    unsigned short* Pp   = (unsigned short*)(ws + 5258752);    // 2,560,000 B
    unsigned short* Qp   = (unsigned short*)(ws + 7818752);    // 2,560,000 B

    hipMemsetAsync(ws, 0, 5160000, stream);                    // sums + cnt
    prep_pq<<<192 + NN / 16, 256, 0, stream>>>(W1, W2, W3, b1, x, WT, Pp, Qp);
    edge_mfma<<<EBLK4, 512, 0, stream>>>(ea, ei, WT, Pp, Qp, b2, b3, sums, cnt);
    node_fused<<<NN / 8, 256, 0, stream>>>(x, sums, cnt, F1, bf1, F2, bf2,
                                           g0, be0, g1, be1, out);
}